// Round 6
// baseline (118.101 us; speedup 1.0000x reference)
//
#include <hip/hip_runtime.h>

#define NB_MAX 64
#define THREADS 256
#define MAX_BLOCKS 2048

// searchsorted(edges, x, 'left') for near-uniform edges: arithmetic guess,
// verified exactly against the true edges (+/-1 window). Exact: absmax 0 in R3-R5.
__device__ __forceinline__ float bin_weight(float x, const float* s_edges,
                                            const float* s_w, int nb, float gs)
{
    int g = (int)ceilf(x * gs);
    g = g < 1 ? 1 : (g > nb - 1 ? nb - 1 : g);
    float eg   = s_edges[g];
    float egm1 = s_edges[g - 1];
    int lo = (eg < x) ? (g + 1) : ((egm1 < x) ? g : (g - 1));
    lo = lo < 1 ? 1 : (lo > nb ? nb : lo);
    return s_w[lo - 1];          // MIN_WEIGHT pre-applied in LDS
}

// log2-space BCE row sum for one D=16 row held in registers.
__device__ __forceinline__ float row16_nll(const float4* P, const float4* T)
{
    const float EPS = 1e-7f;
    const float PHI = 0.99999994f;   // f32(1 - 1e-7)
    float sA = 0.0f, sB = 0.0f;
    #pragma unroll
    for (int j = 0; j < 4; ++j) {
        #pragma unroll
        for (int k = 0; k < 4; ++k) {
            float p = ((const float*)&P[j])[k];
            float t = ((const float*)&T[j])[k];
            p = __builtin_amdgcn_fmed3f(p, EPS, PHI);
            float lp = __log2f(p);
            float lq = __log2f(1.0f - p);   // 1-p exact for p>=0.5 (Sterbenz)
            sA += lq;
            sB = fmaf(t, lp - lq, sB);
        }
    }
    return sA + sB;
}

// R4's best-measured main loop (row-per-thread, 2-row unroll, loads-first)
// + fused last-block-done final reduction (saves the 2nd launch round-trip).
__global__ __launch_bounds__(THREADS)
void wbce_row16_fused_kernel(const float* __restrict__ y_pred,
                             const float* __restrict__ y_true,
                             const float* __restrict__ bin_weights,
                             const float* __restrict__ cond,
                             const float* __restrict__ bin_edges,
                             float* __restrict__ partials,
                             unsigned int* __restrict__ counter,
                             float* __restrict__ out,
                             long long nrows, int nb, float final_scale)
{
    __shared__ float s_edges[NB_MAX];
    __shared__ float s_w[NB_MAX];
    int tid = threadIdx.x;
    if (tid < nb) {
        s_edges[tid] = bin_edges[tid];
        s_w[tid] = fmaxf(bin_weights[tid], 0.01f);
    }
    __syncthreads();

    const float gs = (float)(nb - 1);
    const float4* __restrict__ yp4 = (const float4*)y_pred;
    const float4* __restrict__ yt4 = (const float4*)y_true;

    float acc0 = 0.0f, acc1 = 0.0f;
    long long stride = (long long)gridDim.x * blockDim.x;
    long long r = (long long)blockIdx.x * blockDim.x + tid;

    for (; r + stride < nrows; r += 2 * stride) {
        long long r2 = r + stride;
        // issue everything up front: 2 cond + 16 float4 loads (2 round-trips in flight)
        float x0 = cond[r];
        float x1 = cond[r2];
        float4 P0[4], T0[4], P1[4], T1[4];
        #pragma unroll
        for (int j = 0; j < 4; ++j) {
            P0[j] = yp4[(r  << 2) + j];
            T0[j] = yt4[(r  << 2) + j];
            P1[j] = yp4[(r2 << 2) + j];
            T1[j] = yt4[(r2 << 2) + j];
        }
        float w0 = bin_weight(x0, s_edges, s_w, nb, gs);
        float w1 = bin_weight(x1, s_edges, s_w, nb, gs);
        acc0 = fmaf(-w0, row16_nll(P0, T0), acc0);
        acc1 = fmaf(-w1, row16_nll(P1, T1), acc1);
    }
    if (r < nrows) {   // at most one leftover row per thread
        float x0 = cond[r];
        float4 P0[4], T0[4];
        #pragma unroll
        for (int j = 0; j < 4; ++j) {
            P0[j] = yp4[(r << 2) + j];
            T0[j] = yt4[(r << 2) + j];
        }
        float w0 = bin_weight(x0, s_edges, s_w, nb, gs);
        acc0 = fmaf(-w0, row16_nll(P0, T0), acc0);
    }
    float acc = acc0 + acc1;   // log2-space; *ln2 folded into final_scale

    // wave (64-lane) shuffle reduce
    #pragma unroll
    for (int off = 32; off > 0; off >>= 1)
        acc += __shfl_down(acc, off, 64);

    __shared__ float s_red[THREADS / 64];
    __shared__ int s_last;
    int wave = tid >> 6;
    int lane = tid & 63;
    if (lane == 0) s_red[wave] = acc;
    __syncthreads();
    if (tid == 0) {
        float b = 0.0f;
        #pragma unroll
        for (int w2 = 0; w2 < THREADS / 64; ++w2) b += s_red[w2];
        partials[blockIdx.x] = b;
        __threadfence();                       // release partial (device scope)
        unsigned old = atomicAdd(counter, 1u);
        s_last = (old == gridDim.x - 1) ? 1 : 0;
    }
    __syncthreads();

    if (s_last) {                              // exactly one block runs this
        __threadfence();                       // acquire all partials
        const volatile float* vp = (const volatile float*)partials;
        float a = 0.0f;
        for (int i = tid; i < (int)gridDim.x; i += THREADS) a += vp[i];
        #pragma unroll
        for (int off = 32; off > 0; off >>= 1)
            a += __shfl_down(a, off, 64);
        if (lane == 0) s_red[wave] = a;
        __syncthreads();
        if (tid == 0) {
            float b = 0.0f;
            #pragma unroll
            for (int w2 = 0; w2 < THREADS / 64; ++w2) b += s_red[w2];
            out[0] = b * final_scale;          // * ln2 / count
        }
    }
}

// Generic fallback (any D multiple of 4), two-launch version for safety.
__global__ __launch_bounds__(THREADS)
void wbce_generic_kernel(const float* __restrict__ y_pred,
                         const float* __restrict__ y_true,
                         const float* __restrict__ bin_weights,
                         const float* __restrict__ cond,
                         const float* __restrict__ bin_edges,
                         float* __restrict__ partials,
                         long long nrows, int dq, int nb)
{
    __shared__ float s_edges[NB_MAX];
    __shared__ float s_w[NB_MAX];
    int tid = threadIdx.x;
    if (tid < nb) {
        s_edges[tid] = bin_edges[tid];
        s_w[tid] = fmaxf(bin_weights[tid], 0.01f);
    }
    __syncthreads();

    const float EPS = 1e-7f, PHI = 0.99999994f;
    const float gs = (float)(nb - 1);

    float acc = 0.0f;
    long long stride = (long long)gridDim.x * blockDim.x;
    for (long long r = (long long)blockIdx.x * blockDim.x + tid; r < nrows; r += stride) {
        float x = cond[r];
        float w = bin_weight(x, s_edges, s_w, nb, gs);
        const float4* yp4 = (const float4*)y_pred + (long long)r * dq;
        const float4* yt4 = (const float4*)y_true + (long long)r * dq;
        float sA = 0.0f, sB = 0.0f;
        for (int j = 0; j < dq; ++j) {
            float4 p4 = yp4[j], t4 = yt4[j];
            #pragma unroll
            for (int k = 0; k < 4; ++k) {
                float p = ((const float*)&p4)[k];
                float t = ((const float*)&t4)[k];
                p = __builtin_amdgcn_fmed3f(p, EPS, PHI);
                float lp = __log2f(p);
                float lq = __log2f(1.0f - p);
                sA += lq;
                sB = fmaf(t, lp - lq, sB);
            }
        }
        acc = fmaf(-w, sA + sB, acc);
    }

    #pragma unroll
    for (int off = 32; off > 0; off >>= 1)
        acc += __shfl_down(acc, off, 64);

    __shared__ float s_red[THREADS / 64];
    int wave = tid >> 6;
    int lane = tid & 63;
    if (lane == 0) s_red[wave] = acc;
    __syncthreads();
    if (tid == 0) {
        float b = 0.0f;
        #pragma unroll
        for (int w2 = 0; w2 < THREADS / 64; ++w2) b += s_red[w2];
        partials[blockIdx.x] = b;
    }
}

__global__ __launch_bounds__(THREADS)
void wbce_final_kernel(const float* __restrict__ partials, int n,
                       float* __restrict__ out, float final_scale)
{
    int tid = threadIdx.x;
    float acc = 0.0f;
    for (int i = tid; i < n; i += THREADS) acc += partials[i];

    #pragma unroll
    for (int off = 32; off > 0; off >>= 1)
        acc += __shfl_down(acc, off, 64);

    __shared__ float s_red[THREADS / 64];
    int wave = tid >> 6;
    int lane = tid & 63;
    if (lane == 0) s_red[wave] = acc;
    __syncthreads();
    if (tid == 0) {
        float b = 0.0f;
        #pragma unroll
        for (int w2 = 0; w2 < THREADS / 64; ++w2) b += s_red[w2];
        out[0] = b * final_scale;
    }
}

extern "C" void kernel_launch(void* const* d_in, const int* in_sizes, int n_in,
                              void* d_out, int out_size, void* d_ws, size_t ws_size,
                              hipStream_t stream) {
    const float* y_pred = (const float*)d_in[0];
    const float* y_true = (const float*)d_in[1];
    const float* bw     = (const float*)d_in[2];
    const float* cond   = (const float*)d_in[3];
    const float* edges  = (const float*)d_in[4];

    long long total = in_sizes[0];          // B*D
    long long Bn    = in_sizes[3];          // B
    int D  = (int)(total / Bn);
    int nb = in_sizes[2];

    float* partials = (float*)d_ws;
    unsigned int* counter = (unsigned int*)((char*)d_ws + MAX_BLOCKS * sizeof(float));

    long long want = (Bn + THREADS - 1) / THREADS;
    int grid = (int)(want < MAX_BLOCKS ? want : MAX_BLOCKS);
    if (grid < 1) grid = 1;

    const double LN2 = 0.6931471805599453;
    float final_scale = (float)(LN2 / (double)total);

    if (D == 16) {
        hipMemsetAsync(counter, 0, sizeof(unsigned int), stream);
        wbce_row16_fused_kernel<<<grid, THREADS, 0, stream>>>(
            y_pred, y_true, bw, cond, edges, partials, counter, (float*)d_out,
            Bn, nb, final_scale);
    } else {
        wbce_generic_kernel<<<grid, THREADS, 0, stream>>>(
            y_pred, y_true, bw, cond, edges, partials, Bn, D / 4, nb);
        wbce_final_kernel<<<1, THREADS, 0, stream>>>(partials, grid, (float*)d_out, final_scale);
    }
}

// Round 7
// 46.767 us; speedup vs baseline: 2.5253x; 2.5253x over previous
//
#include <hip/hip_runtime.h>

#define NB_MAX 64
#define THREADS 256
#define MAX_BLOCKS 2048

// searchsorted(edges, x, 'left') for near-uniform edges: arithmetic guess,
// verified exactly against the true edges (+/-1 window). Exact: absmax 0 in R3-R6.
__device__ __forceinline__ float bin_weight(float x, const float* s_edges,
                                            const float* s_w, int nb, float gs)
{
    int g = (int)ceilf(x * gs);
    g = g < 1 ? 1 : (g > nb - 1 ? nb - 1 : g);
    float eg   = s_edges[g];
    float egm1 = s_edges[g - 1];
    int lo = (eg < x) ? (g + 1) : ((egm1 < x) ? g : (g - 1));
    lo = lo < 1 ? 1 : (lo > nb ? nb : lo);
    return s_w[lo - 1];          // MIN_WEIGHT pre-applied in LDS
}

// log2-space BCE row sum for one D=16 row held in registers.
__device__ __forceinline__ float row16_nll(const float4* P, const float4* T)
{
    const float EPS = 1e-7f;
    const float PHI = 0.99999994f;   // f32(1 - 1e-7)
    float sA = 0.0f, sB = 0.0f;
    #pragma unroll
    for (int j = 0; j < 4; ++j) {
        #pragma unroll
        for (int k = 0; k < 4; ++k) {
            float p = ((const float*)&P[j])[k];
            float t = ((const float*)&T[j])[k];
            p = __builtin_amdgcn_fmed3f(p, EPS, PHI);
            float lp = __log2f(p);
            float lq = __log2f(1.0f - p);   // 1-p exact for p>=0.5
            sA += lq;
            sB = fmaf(t, lp - lq, sB);
        }
    }
    return sA + sB;
}

// Best-measured structure (R4, 48.0 us): row-per-thread, 2-row unroll,
// all loads issued up front, two-launch reduction (NO fused atomic epilogue —
// device-scope fence+atomic tail costs ~70 us with a fully co-resident grid).
__global__ __launch_bounds__(THREADS)
void wbce_row16_kernel(const float* __restrict__ y_pred,
                       const float* __restrict__ y_true,
                       const float* __restrict__ bin_weights,
                       const float* __restrict__ cond,
                       const float* __restrict__ bin_edges,
                       float* __restrict__ partials,
                       long long nrows, int nb)
{
    __shared__ float s_edges[NB_MAX];
    __shared__ float s_w[NB_MAX];
    int tid = threadIdx.x;
    if (tid < nb) {
        s_edges[tid] = bin_edges[tid];
        s_w[tid] = fmaxf(bin_weights[tid], 0.01f);
    }
    __syncthreads();

    const float gs = (float)(nb - 1);
    const float4* __restrict__ yp4 = (const float4*)y_pred;
    const float4* __restrict__ yt4 = (const float4*)y_true;

    float acc0 = 0.0f, acc1 = 0.0f;
    long long stride = (long long)gridDim.x * blockDim.x;
    long long r = (long long)blockIdx.x * blockDim.x + tid;

    for (; r + stride < nrows; r += 2 * stride) {
        long long r2 = r + stride;
        // issue everything up front: 2 cond + 16 float4 loads
        float x0 = cond[r];
        float x1 = cond[r2];
        float4 P0[4], T0[4], P1[4], T1[4];
        #pragma unroll
        for (int j = 0; j < 4; ++j) {
            P0[j] = yp4[(r  << 2) + j];
            T0[j] = yt4[(r  << 2) + j];
            P1[j] = yp4[(r2 << 2) + j];
            T1[j] = yt4[(r2 << 2) + j];
        }
        float w0 = bin_weight(x0, s_edges, s_w, nb, gs);
        float w1 = bin_weight(x1, s_edges, s_w, nb, gs);
        acc0 = fmaf(-w0, row16_nll(P0, T0), acc0);
        acc1 = fmaf(-w1, row16_nll(P1, T1), acc1);
    }
    if (r < nrows) {   // at most one leftover row per thread
        float x0 = cond[r];
        float4 P0[4], T0[4];
        #pragma unroll
        for (int j = 0; j < 4; ++j) {
            P0[j] = yp4[(r << 2) + j];
            T0[j] = yt4[(r << 2) + j];
        }
        float w0 = bin_weight(x0, s_edges, s_w, nb, gs);
        acc0 = fmaf(-w0, row16_nll(P0, T0), acc0);
    }
    float acc = acc0 + acc1;   // log2-space; *ln2 folded into final scale

    #pragma unroll
    for (int off = 32; off > 0; off >>= 1)
        acc += __shfl_down(acc, off, 64);

    __shared__ float s_red[THREADS / 64];
    int wave = tid >> 6;
    int lane = tid & 63;
    if (lane == 0) s_red[wave] = acc;
    __syncthreads();
    if (tid == 0) {
        float b = 0.0f;
        #pragma unroll
        for (int w2 = 0; w2 < THREADS / 64; ++w2) b += s_red[w2];
        partials[blockIdx.x] = b;
    }
}

// Generic fallback (any D multiple of 4).
__global__ __launch_bounds__(THREADS)
void wbce_generic_kernel(const float* __restrict__ y_pred,
                         const float* __restrict__ y_true,
                         const float* __restrict__ bin_weights,
                         const float* __restrict__ cond,
                         const float* __restrict__ bin_edges,
                         float* __restrict__ partials,
                         long long nrows, int dq, int nb)
{
    __shared__ float s_edges[NB_MAX];
    __shared__ float s_w[NB_MAX];
    int tid = threadIdx.x;
    if (tid < nb) {
        s_edges[tid] = bin_edges[tid];
        s_w[tid] = fmaxf(bin_weights[tid], 0.01f);
    }
    __syncthreads();

    const float EPS = 1e-7f, PHI = 0.99999994f;
    const float gs = (float)(nb - 1);

    float acc = 0.0f;
    long long stride = (long long)gridDim.x * blockDim.x;
    for (long long r = (long long)blockIdx.x * blockDim.x + tid; r < nrows; r += stride) {
        float x = cond[r];
        float w = bin_weight(x, s_edges, s_w, nb, gs);
        const float4* yp4 = (const float4*)y_pred + (long long)r * dq;
        const float4* yt4 = (const float4*)y_true + (long long)r * dq;
        float sA = 0.0f, sB = 0.0f;
        for (int j = 0; j < dq; ++j) {
            float4 p4 = yp4[j], t4 = yt4[j];
            #pragma unroll
            for (int k = 0; k < 4; ++k) {
                float p = ((const float*)&p4)[k];
                float t = ((const float*)&t4)[k];
                p = __builtin_amdgcn_fmed3f(p, EPS, PHI);
                float lp = __log2f(p);
                float lq = __log2f(1.0f - p);
                sA += lq;
                sB = fmaf(t, lp - lq, sB);
            }
        }
        acc = fmaf(-w, sA + sB, acc);
    }

    #pragma unroll
    for (int off = 32; off > 0; off >>= 1)
        acc += __shfl_down(acc, off, 64);

    __shared__ float s_red[THREADS / 64];
    int wave = tid >> 6;
    int lane = tid & 63;
    if (lane == 0) s_red[wave] = acc;
    __syncthreads();
    if (tid == 0) {
        float b = 0.0f;
        #pragma unroll
        for (int w2 = 0; w2 < THREADS / 64; ++w2) b += s_red[w2];
        partials[blockIdx.x] = b;
    }
}

__global__ __launch_bounds__(THREADS)
void wbce_final_kernel(const float* __restrict__ partials, int n,
                       float* __restrict__ out, float final_scale)
{
    int tid = threadIdx.x;
    float acc = 0.0f;
    for (int i = tid; i < n; i += THREADS) acc += partials[i];

    #pragma unroll
    for (int off = 32; off > 0; off >>= 1)
        acc += __shfl_down(acc, off, 64);

    __shared__ float s_red[THREADS / 64];
    int wave = tid >> 6;
    int lane = tid & 63;
    if (lane == 0) s_red[wave] = acc;
    __syncthreads();
    if (tid == 0) {
        float b = 0.0f;
        #pragma unroll
        for (int w2 = 0; w2 < THREADS / 64; ++w2) b += s_red[w2];
        out[0] = b * final_scale;   // * ln2 / count
    }
}

extern "C" void kernel_launch(void* const* d_in, const int* in_sizes, int n_in,
                              void* d_out, int out_size, void* d_ws, size_t ws_size,
                              hipStream_t stream) {
    const float* y_pred = (const float*)d_in[0];
    const float* y_true = (const float*)d_in[1];
    const float* bw     = (const float*)d_in[2];
    const float* cond   = (const float*)d_in[3];
    const float* edges  = (const float*)d_in[4];

    long long total = in_sizes[0];          // B*D
    long long Bn    = in_sizes[3];          // B
    int D  = (int)(total / Bn);
    int nb = in_sizes[2];

    float* partials = (float*)d_ws;

    long long want = (Bn + THREADS - 1) / THREADS;
    int grid = (int)(want < MAX_BLOCKS ? want : MAX_BLOCKS);
    if (grid < 1) grid = 1;

    if (D == 16) {
        wbce_row16_kernel<<<grid, THREADS, 0, stream>>>(
            y_pred, y_true, bw, cond, edges, partials, Bn, nb);
    } else {
        wbce_generic_kernel<<<grid, THREADS, 0, stream>>>(
            y_pred, y_true, bw, cond, edges, partials, Bn, D / 4, nb);
    }

    const double LN2 = 0.6931471805599453;
    float final_scale = (float)(LN2 / (double)total);
    wbce_final_kernel<<<1, THREADS, 0, stream>>>(partials, grid, (float*)d_out, final_scale);
}